// Round 7
// baseline (1153.671 us; speedup 1.0000x reference)
//
#include <hip/hip_runtime.h>

// GRU with per-row sequence lengths. B=4096, T=200, I=64, H=128 (hardcoded).
// Output[b] = h after seq_lengths[b] steps from h0=0.
//
// Round-7 structure: 512 blocks x 512 threads, 8 REAL rows/block ->
// 2 independent blocks/CU (grid was the occupancy cap before), 4 waves/SIMD,
// de-phased block barriers. Wave owns 16 h-cols (48 gate cols): 12 h-MFMA +
// 6 x-MFMA (x-part pipelined 1 step ahead), B-frags resident (18 x h8).
// M=16 MFMA is half-phantom (rows 8..15):
//  - A-tile rows 8..15 alias ONE shared zeroed row -> LDS broadcast reads
//    (no traffic growth).
//  - phantom lanes' gate math is wave-level free-ish (exec cost accepted).
// exp2-prescale: log2(e) folded into r/z weights+biases, 2*log2(e) into n
// -> sigmoid/tanh are raw v_exp/v_rcp, no range-scaling muls.
// x staged in 8-step LDS ring, stagger (t&7)==blockIdx%7. __syncthreads only.

#define I_DIM 64
#define H_DIM 128
#define ROWS 8   // real batch rows per block
#define CH 8     // x-chunk steps
#define RS 40    // slab row stride in halves (80 B)
#define LOG2E 1.44269504088896f

typedef _Float16 h8 __attribute__((ext_vector_type(8)));
typedef _Float16 h4 __attribute__((ext_vector_type(4)));
typedef float f4 __attribute__((ext_vector_type(4)));

__device__ __forceinline__ float sig2(float xp) {   // xp pre-scaled by log2e
    return __builtin_amdgcn_rcpf(1.0f + __builtin_amdgcn_exp2f(-xp));
}
__device__ __forceinline__ float tanh2(float ap) {  // ap pre-scaled by 2*log2e
    return 1.0f - 2.0f * __builtin_amdgcn_rcpf(__builtin_amdgcn_exp2f(ap) + 1.0f);
}

__global__ __launch_bounds__(512, 4)
void gru_seq_kernel(const float* __restrict__ input,
                    const int* __restrict__ seq_lengths,
                    const float* __restrict__ W_ih,
                    const float* __restrict__ W_hh,
                    const float* __restrict__ b_ih,
                    const float* __restrict__ b_hh,
                    float* __restrict__ out,
                    int B, int T) {
    // h: [buf][slab k/32][row 0..7 + zero-row 8][RS]
    // x ring: [slot][step][slab][row 0..7 + zero-row 8][RS]
    __shared__ __align__(16) _Float16 h_lds[2][4][ROWS + 1][RS];
    __shared__ __align__(16) _Float16 x_lds[2][CH][2][ROWS + 1][RS];

    const int tid  = threadIdx.x;
    const int lane = tid & 63;
    const int w    = tid >> 6;     // wave 0..7
    const int base = blockIdx.x * ROWS;
    const int boff = blockIdx.x % 7;   // stage-phase stagger

    const int lrow  = lane & 15;   // MFMA A-row / C-col index
    const int kgrp  = lane >> 4;   // 0..3
    const int kgrp8 = kgrp * 8;
    const int kgrp4 = kgrp * 4;
    const int arow  = (lrow < ROWS) ? lrow : ROWS;   // phantom rows -> zero row

    // ---- sequence lengths (C rows kgrp4+q; real iff < ROWS) ----
    int Lq[4];
#pragma unroll
    for (int q = 0; q < 4; ++q) {
        int r  = kgrp4 + q;
        int gr = base + r;
        Lq[q] = (r < ROWS && gr < B) ? seq_lengths[gr] : 0;
    }
    int Lmax = 0;
    for (int i = 0; i < ROWS; ++i) {
        int gr = base + i;
        int L = (gr < B) ? seq_lengths[gr] : 0;
        Lmax = max(Lmax, L);
    }
    if (Lmax > T) Lmax = T;

    // ---- biases, exp2-prescaled (C col = w*16 + lrow) ----
    const int c0 = w * 16 + lrow;
    const float br  = (b_ih[c0] + b_hh[c0]) * LOG2E;
    const float bz  = (b_ih[H_DIM + c0] + b_hh[H_DIM + c0]) * LOG2E;
    const float bnh = b_hh[2 * H_DIM + c0] * (2.0f * LOG2E);
    const float bnx = b_ih[2 * H_DIM + c0] * (2.0f * LOG2E);

    // ---- resident B-fragments, exp2-prescaled per gate ----
    h8 bw[18];
#pragma unroll
    for (int gate = 0; gate < 3; ++gate) {
        const float gs = (gate == 2) ? (2.0f * LOG2E) : LOG2E;
        const int j = gate * H_DIM + c0;
#pragma unroll
        for (int kt = 0; kt < 6; ++kt) {
            const int kb = kt * 32 + kgrp8;
            const float* src = (kt < 4) ? (W_hh + j * H_DIM + kb)
                                        : (W_ih + j * I_DIM + (kb - H_DIM));
            f4 f0 = *(const f4*)(src);
            f4 f1 = *(const f4*)(src + 4);
            h8 v;
            v[0] = (_Float16)(f0[0] * gs); v[1] = (_Float16)(f0[1] * gs);
            v[2] = (_Float16)(f0[2] * gs); v[3] = (_Float16)(f0[3] * gs);
            v[4] = (_Float16)(f1[0] * gs); v[5] = (_Float16)(f1[1] * gs);
            v[6] = (_Float16)(f1[2] * gs); v[7] = (_Float16)(f1[3] * gs);
            bw[gate * 6 + kt] = v;
        }
    }

    // ---- zero ALL LDS (zero rows + h(0)=0 + x ring padding) ----
    {
        h8 z = h8{0, 0, 0, 0, 0, 0, 0, 0};
        h8* ph = (h8*)&h_lds[0][0][0][0];
        const int nh = (int)(sizeof(h_lds) / sizeof(h8));
        for (int i = tid; i < nh; i += 512) ph[i] = z;
        h8* px = (h8*)&x_lds[0][0][0][0][0];
        const int nx = (int)(sizeof(x_lds) / sizeof(h8));
        for (int i = tid; i < nx; i += 512) px[i] = z;
    }
    __syncthreads();

    // ---- x staging geometry: wave w loads row w; lane covers step (lane>>3)&7,
    //      8 floats at col (lane&7)*8 ----
    const int srow  = w;                      // 0..7
    const int sstep = (lane >> 3) & 7;        // 0..7
    const int sc    = (lane & 7) * 8;         // 0,8,..,56
    const int sslab = sc >> 5;
    const int scol  = sc & 31;
    const float* xsrc = input + (size_t)(base + srow) * T * I_DIM;
    const bool xok = (base + srow) < B;

    // prologue: stage chunk 0 into slot 0
    if (Lmax > 0) {
        f4 a = f4{0.f, 0.f, 0.f, 0.f}, b = f4{0.f, 0.f, 0.f, 0.f};
        if (xok && sstep < T) {
            a = *(const f4*)(xsrc + (size_t)sstep * I_DIM + sc);
            b = *(const f4*)(xsrc + (size_t)sstep * I_DIM + sc + 4);
        }
        h4 ha, hb;
        ha[0] = (_Float16)a[0]; ha[1] = (_Float16)a[1];
        ha[2] = (_Float16)a[2]; ha[3] = (_Float16)a[3];
        hb[0] = (_Float16)b[0]; hb[1] = (_Float16)b[1];
        hb[2] = (_Float16)b[2]; hb[3] = (_Float16)b[3];
        *(h4*)&x_lds[0][sstep][sslab][srow][scol]     = ha;
        *(h4*)&x_lds[0][sstep][sslab][srow][scol + 4] = hb;
    }
    __syncthreads();

    // ---- x-part accumulators (ping-pong by step parity), prologue fills set 0 ----
    f4 xar[2], xaz[2], xan[2];
    xar[0] = f4{br, br, br, br};
    xaz[0] = f4{bz, bz, bz, bz};
    xan[0] = f4{bnx, bnx, bnx, bnx};
    if (Lmax > 0) {
        h8 xg0 = *(const h8*)&x_lds[0][0][0][arow][kgrp8];
        h8 xg1 = *(const h8*)&x_lds[0][0][1][arow][kgrp8];
        xar[0] = __builtin_amdgcn_mfma_f32_16x16x32_f16(xg0, bw[4],  xar[0], 0, 0, 0);
        xar[0] = __builtin_amdgcn_mfma_f32_16x16x32_f16(xg1, bw[5],  xar[0], 0, 0, 0);
        xaz[0] = __builtin_amdgcn_mfma_f32_16x16x32_f16(xg0, bw[10], xaz[0], 0, 0, 0);
        xaz[0] = __builtin_amdgcn_mfma_f32_16x16x32_f16(xg1, bw[11], xaz[0], 0, 0, 0);
        xan[0] = __builtin_amdgcn_mfma_f32_16x16x32_f16(xg0, bw[16], xan[0], 0, 0, 0);
        xan[0] = __builtin_amdgcn_mfma_f32_16x16x32_f16(xg1, bw[17], xan[0], 0, 0, 0);
    }

    const int hs = c0 >> 5;     // h-write slab
    const int hc = c0 & 31;     // h-write col within slab

    float hreg[4]  = {0.f, 0.f, 0.f, 0.f};
    float hnreg[4] = {0.f, 0.f, 0.f, 0.f};

#define STEP(P, TC) do {                                                              \
        const int t_ = (TC);                                                          \
        f4 xva, xvb;                                                                  \
        const bool do_stage = ((t_ & 7) == boff) && (((t_ >> 3) + 1) * CH < Lmax);    \
        if (do_stage) {                                                               \
            const int s_ = ((t_ >> 3) + 1) * CH + sstep;                              \
            xva = xvb = f4{0.f, 0.f, 0.f, 0.f};                                       \
            if (xok && s_ < T) {                                                      \
                xva = *(const f4*)(xsrc + (size_t)s_ * I_DIM + sc);                   \
                xvb = *(const f4*)(xsrc + (size_t)s_ * I_DIM + sc + 4);               \
            }                                                                         \
        }                                                                             \
        h8 af0 = *(const h8*)&h_lds[P][0][arow][kgrp8];                               \
        h8 af1 = *(const h8*)&h_lds[P][1][arow][kgrp8];                               \
        h8 af2 = *(const h8*)&h_lds[P][2][arow][kgrp8];                               \
        h8 af3 = *(const h8*)&h_lds[P][3][arow][kgrp8];                               \
        f4 ar  = xar[P];                                                              \
        f4 az  = xaz[P];                                                              \
        f4 axn = xan[P];                                                              \
        f4 anh = f4{bnh, bnh, bnh, bnh};                                              \
        __builtin_amdgcn_s_setprio(1);                                                \
        ar  = __builtin_amdgcn_mfma_f32_16x16x32_f16(af0, bw[0],  ar,  0, 0, 0);      \
        az  = __builtin_amdgcn_mfma_f32_16x16x32_f16(af0, bw[6],  az,  0, 0, 0);      \
        anh = __builtin_amdgcn_mfma_f32_16x16x32_f16(af0, bw[12], anh, 0, 0, 0);      \
        ar  = __builtin_amdgcn_mfma_f32_16x16x32_f16(af1, bw[1],  ar,  0, 0, 0);      \
        az  = __builtin_amdgcn_mfma_f32_16x16x32_f16(af1, bw[7],  az,  0, 0, 0);      \
        anh = __builtin_amdgcn_mfma_f32_16x16x32_f16(af1, bw[13], anh, 0, 0, 0);      \
        ar  = __builtin_amdgcn_mfma_f32_16x16x32_f16(af2, bw[2],  ar,  0, 0, 0);      \
        az  = __builtin_amdgcn_mfma_f32_16x16x32_f16(af2, bw[8],  az,  0, 0, 0);      \
        anh = __builtin_amdgcn_mfma_f32_16x16x32_f16(af2, bw[14], anh, 0, 0, 0);      \
        ar  = __builtin_amdgcn_mfma_f32_16x16x32_f16(af3, bw[3],  ar,  0, 0, 0);      \
        az  = __builtin_amdgcn_mfma_f32_16x16x32_f16(af3, bw[9],  az,  0, 0, 0);      \
        anh = __builtin_amdgcn_mfma_f32_16x16x32_f16(af3, bw[15], anh, 0, 0, 0);      \
        if (t_ + 1 < Lmax) {   /* x-part for step t+1 (independent) */                \
            const int sl_ = ((t_ + 1) >> 3) & 1, ss_ = (t_ + 1) & 7;                  \
            h8 xg0 = *(const h8*)&x_lds[sl_][ss_][0][arow][kgrp8];                    \
            h8 xg1 = *(const h8*)&x_lds[sl_][ss_][1][arow][kgrp8];                    \
            f4 a0 = f4{br, br, br, br};                                               \
            f4 a1 = f4{bz, bz, bz, bz};                                               \
            f4 a2 = f4{bnx, bnx, bnx, bnx};                                           \
            a0 = __builtin_amdgcn_mfma_f32_16x16x32_f16(xg0, bw[4],  a0, 0, 0, 0);    \
            a1 = __builtin_amdgcn_mfma_f32_16x16x32_f16(xg0, bw[10], a1, 0, 0, 0);    \
            a2 = __builtin_amdgcn_mfma_f32_16x16x32_f16(xg0, bw[16], a2, 0, 0, 0);    \
            a0 = __builtin_amdgcn_mfma_f32_16x16x32_f16(xg1, bw[5],  a0, 0, 0, 0);    \
            a1 = __builtin_amdgcn_mfma_f32_16x16x32_f16(xg1, bw[11], a1, 0, 0, 0);    \
            a2 = __builtin_amdgcn_mfma_f32_16x16x32_f16(xg1, bw[17], a2, 0, 0, 0);    \
            xar[(P) ^ 1] = a0; xaz[(P) ^ 1] = a1; xan[(P) ^ 1] = a2;                  \
        }                                                                             \
        __builtin_amdgcn_s_setprio(0);                                                \
        _Pragma("unroll")                                                             \
        for (int q = 0; q < 4; ++q) {                                                 \
            float r    = sig2(ar[q]);                                                 \
            float z    = sig2(az[q]);                                                 \
            float n    = tanh2(axn[q] + r * anh[q]);                                  \
            float hnew = n + z * (hreg[q] - n);                                       \
            hreg[q] = hnew;                                                           \
            if (t_ < Lq[q]) hnreg[q] = hnew;                                          \
        }                                                                             \
        if (kgrp < 2) {                                                               \
            _Pragma("unroll")                                                         \
            for (int q = 0; q < 4; ++q)                                               \
                h_lds[(P) ^ 1][hs][kgrp4 + q][hc] = (_Float16)hreg[q];                \
        }                                                                             \
        if (do_stage) {                                                               \
            const int ws_ = ((t_ >> 3) + 1) & 1;                                      \
            h4 ha, hb;                                                                \
            ha[0] = (_Float16)xva[0]; ha[1] = (_Float16)xva[1];                       \
            ha[2] = (_Float16)xva[2]; ha[3] = (_Float16)xva[3];                       \
            hb[0] = (_Float16)xvb[0]; hb[1] = (_Float16)xvb[1];                       \
            hb[2] = (_Float16)xvb[2]; hb[3] = (_Float16)xvb[3];                       \
            *(h4*)&x_lds[ws_][sstep][sslab][srow][scol]     = ha;                     \
            *(h4*)&x_lds[ws_][sstep][sslab][srow][scol + 4] = hb;                     \
        }                                                                             \
        __syncthreads();                                                              \
    } while (0)

    int t = 0;
    for (; t + 1 < Lmax; t += 2) {
        STEP(0, t);
        STEP(1, t + 1);
    }
    if (t < Lmax) STEP(0, t);

#undef STEP

    // ---- store hn (real rows only) ----
    if (kgrp < 2) {
#pragma unroll
        for (int q = 0; q < 4; ++q) {
            int gr = base + kgrp4 + q;
            if (gr < B) out[(size_t)gr * H_DIM + c0] = hnreg[q];
        }
    }
}

extern "C" void kernel_launch(void* const* d_in, const int* in_sizes, int n_in,
                              void* d_out, int out_size, void* d_ws, size_t ws_size,
                              hipStream_t stream) {
    const float* input = (const float*)d_in[0];
    const int*   seq   = (const int*)d_in[1];
    const float* W_ih  = (const float*)d_in[2];
    const float* W_hh  = (const float*)d_in[3];
    const float* b_ih  = (const float*)d_in[4];
    const float* b_hh  = (const float*)d_in[5];
    float* out = (float*)d_out;

    const int B = in_sizes[1];
    const int T = in_sizes[0] / (B * I_DIM);

    const int grid = (B + ROWS - 1) / ROWS;
    gru_seq_kernel<<<grid, 512, 0, stream>>>(input, seq, W_ih, W_hh, b_ih, b_hh, out, B, T);
}

// Round 8
// 290.114 us; speedup vs baseline: 3.9766x; 3.9766x over previous
//
#include <hip/hip_runtime.h>

// GRU with per-row sequence lengths. B=4096, T=200, I=64, H=128 (hardcoded).
// Output[b] = h after seq_lengths[b] steps from h0=0.
//
// Round-8 structure: 256 blocks x 1024 threads (16 waves = 4/SIMD
// STRUCTURALLY -- no launch_bounds min-occupancy hint; r7 showed the
// allocator honors it by spilling: VGPR 64, WRITE_SIZE 815MB).
// 16 REAL rows/block; waves role-split:
//   waves 0-7  (gate role, slice s=w): 4 h-frag ds_reads + 12 h-MFMA
//     (kt0-3 x {r,z,n}) with accumulators INITIALIZED from x-partials read
//     from LDS; gates; h(t+1) write. setprio(1) around MFMA (T5 role-split).
//   waves 8-15 (x role, slice s=w-8): load x(t+1) straight from global
//     (16 rows x 64 f32 = 4KB/step, L1-hot, no LDS ring / staging VALU),
//     6 x-MFMA with bias init, write 3 f16 partials (b64, 2-way = free)
//     one step ahead into parity buffer P^1.
// ONE __syncthreads per step publishes h(t+1) + partials(t+1).
// exp2-prescale folded into weights/biases (raw v_exp2/v_rcp gates).

#define I_DIM 64
#define H_DIM 128
#define RS 40    // h slab row stride in halves (80 B; (20w*lrow+4w*kgrp)%32 spread = minimal banking)
#define LOG2E 1.44269504088896f

typedef _Float16 h8 __attribute__((ext_vector_type(8)));
typedef _Float16 h4 __attribute__((ext_vector_type(4)));
typedef _Float16 h2 __attribute__((ext_vector_type(2)));
typedef float f4 __attribute__((ext_vector_type(4)));

__device__ __forceinline__ float sig2(float xp) {   // xp pre-scaled by log2e
    return __builtin_amdgcn_rcpf(1.0f + __builtin_amdgcn_exp2f(-xp));
}
__device__ __forceinline__ float tanh2(float ap) {  // ap pre-scaled by 2*log2e
    return 1.0f - 2.0f * __builtin_amdgcn_rcpf(__builtin_amdgcn_exp2f(ap) + 1.0f);
}

__global__ __launch_bounds__(1024)
void gru_seq_kernel(const float* __restrict__ input,
                    const int* __restrict__ seq_lengths,
                    const float* __restrict__ W_ih,
                    const float* __restrict__ W_hh,
                    const float* __restrict__ b_ih,
                    const float* __restrict__ b_hh,
                    float* __restrict__ out,
                    int B, int T) {
    // h tile: [parity][slab k/32][row][RS] (only cols 0..31 of RS used)
    __shared__ __align__(16) _Float16 h_lds[2][4][16][RS];
    // x-partials: [parity][gate i][slice][lane][4 f16]  (8B/lane -> b64 ops)
    __shared__ __align__(16) _Float16 p_lds[2][3][8][64][4];

    const int tid  = threadIdx.x;
    const int lane = tid & 63;
    const int w    = tid >> 6;       // 0..15
    const int role = w >> 3;         // 0 = gate waves, 1 = x waves
    const int s    = w & 7;          // column slice
    const int base = blockIdx.x * 16;

    const int lrow  = lane & 15;     // MFMA A-row / C-col index
    const int kgrp  = lane >> 4;     // 0..3
    const int kgrp8 = kgrp * 8;
    const int kgrp4 = kgrp * 4;
    const int c0    = s * 16 + lrow; // h column owned by this lane's slice

    // ---- sequence lengths ----
    int Lmax = 0;
    for (int i = 0; i < 16; ++i) {
        int gr = base + i;
        int L = (gr < B) ? seq_lengths[gr] : 0;
        Lmax = max(Lmax, L);
    }
    if (Lmax > T) Lmax = T;
    int Lq[4];
#pragma unroll
    for (int q = 0; q < 4; ++q) {
        int gr = base + kgrp4 + q;
        Lq[q] = (gr < B) ? seq_lengths[gr] : 0;
    }

    // ---- role-specific weights/biases (shared bw[] storage keeps VGPR low) ----
    float bnh = 0.f, br = 0.f, bz = 0.f, bnx = 0.f;
    h8 bw[12];
    if (role == 0) {
        bnh = b_hh[2 * H_DIM + c0] * (2.f * LOG2E);
#pragma unroll
        for (int g = 0; g < 3; ++g) {
            const float gs = (g == 2) ? (2.f * LOG2E) : LOG2E;
            const float* wr = W_hh + (size_t)(g * H_DIM + c0) * H_DIM;
#pragma unroll
            for (int kt = 0; kt < 4; ++kt) {
                f4 f0 = *(const f4*)(wr + kt * 32 + kgrp8);
                f4 f1 = *(const f4*)(wr + kt * 32 + kgrp8 + 4);
                h8 v;
                v[0] = (_Float16)(f0[0] * gs); v[1] = (_Float16)(f0[1] * gs);
                v[2] = (_Float16)(f0[2] * gs); v[3] = (_Float16)(f0[3] * gs);
                v[4] = (_Float16)(f1[0] * gs); v[5] = (_Float16)(f1[1] * gs);
                v[6] = (_Float16)(f1[2] * gs); v[7] = (_Float16)(f1[3] * gs);
                bw[g * 4 + kt] = v;
            }
        }
    } else {
        br  = (b_ih[c0] + b_hh[c0]) * LOG2E;
        bz  = (b_ih[H_DIM + c0] + b_hh[H_DIM + c0]) * LOG2E;
        bnx = b_ih[2 * H_DIM + c0] * (2.f * LOG2E);
#pragma unroll
        for (int g = 0; g < 3; ++g) {
            const float gs = (g == 2) ? (2.f * LOG2E) : LOG2E;
            const float* wr = W_ih + (size_t)(g * H_DIM + c0) * I_DIM;
#pragma unroll
            for (int kx = 0; kx < 2; ++kx) {
                f4 f0 = *(const f4*)(wr + kx * 32 + kgrp8);
                f4 f1 = *(const f4*)(wr + kx * 32 + kgrp8 + 4);
                h8 v;
                v[0] = (_Float16)(f0[0] * gs); v[1] = (_Float16)(f0[1] * gs);
                v[2] = (_Float16)(f0[2] * gs); v[3] = (_Float16)(f0[3] * gs);
                v[4] = (_Float16)(f1[0] * gs); v[5] = (_Float16)(f1[1] * gs);
                v[6] = (_Float16)(f1[2] * gs); v[7] = (_Float16)(f1[3] * gs);
                bw[g * 2 + kx] = v;
            }
        }
    }

    // x source for x-role lanes: row = base + lrow
    const float* xsrc = input + (size_t)(base + lrow) * T * I_DIM;
    const bool xok = (base + lrow) < B;

    // ---- zero h parity-0 tile (h(0) = 0); 1024 thr x 2 halves = 2048 ----
    {
        int idx = tid * 2;
        int sl = idx >> 9, r = (idx >> 5) & 15, cc = idx & 31;
        *(h2*)&h_lds[0][sl][r][cc] = h2{0, 0};
    }
    __syncthreads();

    // ---- prologue: x waves produce partials(t=0) into parity 0 ----
    if (role == 1 && Lmax > 0) {
        f4 xa = f4{0.f,0.f,0.f,0.f}, xb = xa, xc = xa, xd = xa;
        if (xok) {
            xa = *(const f4*)(xsrc + kgrp8);
            xb = *(const f4*)(xsrc + kgrp8 + 4);
            xc = *(const f4*)(xsrc + 32 + kgrp8);
            xd = *(const f4*)(xsrc + 32 + kgrp8 + 4);
        }
        h8 xg0, xg1;
        xg0[0]=(_Float16)xa[0]; xg0[1]=(_Float16)xa[1]; xg0[2]=(_Float16)xa[2]; xg0[3]=(_Float16)xa[3];
        xg0[4]=(_Float16)xb[0]; xg0[5]=(_Float16)xb[1]; xg0[6]=(_Float16)xb[2]; xg0[7]=(_Float16)xb[3];
        xg1[0]=(_Float16)xc[0]; xg1[1]=(_Float16)xc[1]; xg1[2]=(_Float16)xc[2]; xg1[3]=(_Float16)xc[3];
        xg1[4]=(_Float16)xd[0]; xg1[5]=(_Float16)xd[1]; xg1[6]=(_Float16)xd[2]; xg1[7]=(_Float16)xd[3];
        f4 a0 = f4{br, br, br, br};
        f4 a1 = f4{bz, bz, bz, bz};
        f4 a2 = f4{bnx, bnx, bnx, bnx};
        a0 = __builtin_amdgcn_mfma_f32_16x16x32_f16(xg0, bw[0], a0, 0, 0, 0);
        a1 = __builtin_amdgcn_mfma_f32_16x16x32_f16(xg0, bw[2], a1, 0, 0, 0);
        a2 = __builtin_amdgcn_mfma_f32_16x16x32_f16(xg0, bw[4], a2, 0, 0, 0);
        a0 = __builtin_amdgcn_mfma_f32_16x16x32_f16(xg1, bw[1], a0, 0, 0, 0);
        a1 = __builtin_amdgcn_mfma_f32_16x16x32_f16(xg1, bw[3], a1, 0, 0, 0);
        a2 = __builtin_amdgcn_mfma_f32_16x16x32_f16(xg1, bw[5], a2, 0, 0, 0);
        h4 p;
        p[0]=(_Float16)a0[0]; p[1]=(_Float16)a0[1]; p[2]=(_Float16)a0[2]; p[3]=(_Float16)a0[3];
        *(h4*)&p_lds[0][0][s][lane][0] = p;
        p[0]=(_Float16)a1[0]; p[1]=(_Float16)a1[1]; p[2]=(_Float16)a1[2]; p[3]=(_Float16)a1[3];
        *(h4*)&p_lds[0][1][s][lane][0] = p;
        p[0]=(_Float16)a2[0]; p[1]=(_Float16)a2[1]; p[2]=(_Float16)a2[2]; p[3]=(_Float16)a2[3];
        *(h4*)&p_lds[0][2][s][lane][0] = p;
    }
    __syncthreads();

    const int hs = c0 >> 5;     // h-write slab
    const int hc = c0 & 31;     // h-write col within slab

    float hreg[4]  = {0.f, 0.f, 0.f, 0.f};
    float hnreg[4] = {0.f, 0.f, 0.f, 0.f};

#define STEP(P, TC) do {                                                              \
        const int t_ = (TC);                                                          \
        if (role == 0) {                                                              \
            h8 af0 = *(const h8*)&h_lds[P][0][lrow][kgrp8];                           \
            h8 af1 = *(const h8*)&h_lds[P][1][lrow][kgrp8];                           \
            h8 af2 = *(const h8*)&h_lds[P][2][lrow][kgrp8];                           \
            h8 af3 = *(const h8*)&h_lds[P][3][lrow][kgrp8];                           \
            h4 p0 = *(const h4*)&p_lds[P][0][s][lane][0];                             \
            h4 p1 = *(const h4*)&p_lds[P][1][s][lane][0];                             \
            h4 p2 = *(const h4*)&p_lds[P][2][s][lane][0];                             \
            f4 ar  = f4{(float)p0[0], (float)p0[1], (float)p0[2], (float)p0[3]};      \
            f4 az  = f4{(float)p1[0], (float)p1[1], (float)p1[2], (float)p1[3]};      \
            f4 axn = f4{(float)p2[0], (float)p2[1], (float)p2[2], (float)p2[3]};      \
            f4 anh = f4{bnh, bnh, bnh, bnh};                                          \
            __builtin_amdgcn_s_setprio(1);                                            \
            ar  = __builtin_amdgcn_mfma_f32_16x16x32_f16(af0, bw[0],  ar,  0, 0, 0);  \
            az  = __builtin_amdgcn_mfma_f32_16x16x32_f16(af0, bw[4],  az,  0, 0, 0);  \
            anh = __builtin_amdgcn_mfma_f32_16x16x32_f16(af0, bw[8],  anh, 0, 0, 0);  \
            ar  = __builtin_amdgcn_mfma_f32_16x16x32_f16(af1, bw[1],  ar,  0, 0, 0);  \
            az  = __builtin_amdgcn_mfma_f32_16x16x32_f16(af1, bw[5],  az,  0, 0, 0);  \
            anh = __builtin_amdgcn_mfma_f32_16x16x32_f16(af1, bw[9],  anh, 0, 0, 0);  \
            ar  = __builtin_amdgcn_mfma_f32_16x16x32_f16(af2, bw[2],  ar,  0, 0, 0);  \
            az  = __builtin_amdgcn_mfma_f32_16x16x32_f16(af2, bw[6],  az,  0, 0, 0);  \
            anh = __builtin_amdgcn_mfma_f32_16x16x32_f16(af2, bw[10], anh, 0, 0, 0);  \
            ar  = __builtin_amdgcn_mfma_f32_16x16x32_f16(af3, bw[3],  ar,  0, 0, 0);  \
            az  = __builtin_amdgcn_mfma_f32_16x16x32_f16(af3, bw[7],  az,  0, 0, 0);  \
            anh = __builtin_amdgcn_mfma_f32_16x16x32_f16(af3, bw[11], anh, 0, 0, 0);  \
            __builtin_amdgcn_s_setprio(0);                                            \
            _Pragma("unroll")                                                         \
            for (int q = 0; q < 4; ++q) {                                             \
                float r    = sig2(ar[q]);                                             \
                float z    = sig2(az[q]);                                             \
                float n    = tanh2(axn[q] + r * anh[q]);                              \
                float hnew = n + z * (hreg[q] - n);                                   \
                hreg[q] = hnew;                                                       \
                if (t_ < Lq[q]) hnreg[q] = hnew;                                      \
                h_lds[(P) ^ 1][hs][kgrp4 + q][hc] = (_Float16)hnew;                   \
            }                                                                         \
        } else if (t_ + 1 < Lmax) {                                                   \
            const size_t xo = (size_t)(t_ + 1) * I_DIM;                               \
            f4 xa = f4{0.f,0.f,0.f,0.f}, xb = xa, xc = xa, xd = xa;                   \
            if (xok) {                                                                \
                xa = *(const f4*)(xsrc + xo + kgrp8);                                 \
                xb = *(const f4*)(xsrc + xo + kgrp8 + 4);                             \
                xc = *(const f4*)(xsrc + xo + 32 + kgrp8);                            \
                xd = *(const f4*)(xsrc + xo + 32 + kgrp8 + 4);                        \
            }                                                                         \
            h8 xg0, xg1;                                                              \
            xg0[0]=(_Float16)xa[0]; xg0[1]=(_Float16)xa[1];                           \
            xg0[2]=(_Float16)xa[2]; xg0[3]=(_Float16)xa[3];                           \
            xg0[4]=(_Float16)xb[0]; xg0[5]=(_Float16)xb[1];                           \
            xg0[6]=(_Float16)xb[2]; xg0[7]=(_Float16)xb[3];                           \
            xg1[0]=(_Float16)xc[0]; xg1[1]=(_Float16)xc[1];                           \
            xg1[2]=(_Float16)xc[2]; xg1[3]=(_Float16)xc[3];                           \
            xg1[4]=(_Float16)xd[0]; xg1[5]=(_Float16)xd[1];                           \
            xg1[6]=(_Float16)xd[2]; xg1[7]=(_Float16)xd[3];                           \
            f4 a0 = f4{br, br, br, br};                                               \
            f4 a1 = f4{bz, bz, bz, bz};                                               \
            f4 a2 = f4{bnx, bnx, bnx, bnx};                                           \
            a0 = __builtin_amdgcn_mfma_f32_16x16x32_f16(xg0, bw[0], a0, 0, 0, 0);     \
            a1 = __builtin_amdgcn_mfma_f32_16x16x32_f16(xg0, bw[2], a1, 0, 0, 0);     \
            a2 = __builtin_amdgcn_mfma_f32_16x16x32_f16(xg0, bw[4], a2, 0, 0, 0);     \
            a0 = __builtin_amdgcn_mfma_f32_16x16x32_f16(xg1, bw[1], a0, 0, 0, 0);     \
            a1 = __builtin_amdgcn_mfma_f32_16x16x32_f16(xg1, bw[3], a1, 0, 0, 0);     \
            a2 = __builtin_amdgcn_mfma_f32_16x16x32_f16(xg1, bw[5], a2, 0, 0, 0);     \
            h4 p;                                                                     \
            p[0]=(_Float16)a0[0]; p[1]=(_Float16)a0[1];                               \
            p[2]=(_Float16)a0[2]; p[3]=(_Float16)a0[3];                               \
            *(h4*)&p_lds[(P) ^ 1][0][s][lane][0] = p;                                 \
            p[0]=(_Float16)a1[0]; p[1]=(_Float16)a1[1];                               \
            p[2]=(_Float16)a1[2]; p[3]=(_Float16)a1[3];                               \
            *(h4*)&p_lds[(P) ^ 1][1][s][lane][0] = p;                                 \
            p[0]=(_Float16)a2[0]; p[1]=(_Float16)a2[1];                               \
            p[2]=(_Float16)a2[2]; p[3]=(_Float16)a2[3];                               \
            *(h4*)&p_lds[(P) ^ 1][2][s][lane][0] = p;                                 \
        }                                                                             \
        __syncthreads();                                                              \
    } while (0)

    int t = 0;
    for (; t + 1 < Lmax; t += 2) {
        STEP(0, t);
        STEP(1, t + 1);
    }
    if (t < Lmax) STEP(0, t);

#undef STEP

    // ---- store hn (gate waves own all 128 cols x 16 rows) ----
    if (role == 0) {
#pragma unroll
        for (int q = 0; q < 4; ++q) {
            int gr = base + kgrp4 + q;
            if (gr < B) out[(size_t)gr * H_DIM + c0] = hnreg[q];
        }
    }
}

extern "C" void kernel_launch(void* const* d_in, const int* in_sizes, int n_in,
                              void* d_out, int out_size, void* d_ws, size_t ws_size,
                              hipStream_t stream) {
    const float* input = (const float*)d_in[0];
    const int*   seq   = (const int*)d_in[1];
    const float* W_ih  = (const float*)d_in[2];
    const float* W_hh  = (const float*)d_in[3];
    const float* b_ih  = (const float*)d_in[4];
    const float* b_hh  = (const float*)d_in[5];
    float* out = (float*)d_out;

    const int B = in_sizes[1];
    const int T = in_sizes[0] / (B * I_DIM);

    const int grid = (B + 15) / 16;
    gru_seq_kernel<<<grid, 1024, 0, stream>>>(input, seq, W_ih, W_hh, b_ih, b_hh, out, B, T);
}